// Round 1
// baseline (377.448 us; speedup 1.0000x reference)
//
#include <hip/hip_runtime.h>
#include <hip/hip_bf16.h>

#define B_ 16
#define T_ 1500
#define E_ 512
#define A_ 512
#define H_ 4
#define C_ 10
#define K_ 201
#define M_ (B_*T_)   // 24000

typedef __attribute__((ext_vector_type(8))) short short8v;    // 8 bf16
typedef __attribute__((ext_vector_type(4))) float f32x4;
typedef __attribute__((ext_vector_type(4))) unsigned short ushort4v;
typedef __attribute__((ext_vector_type(8))) unsigned short ushort8v;

__device__ inline unsigned short f2bf(float x) {
    unsigned int u = __float_as_uint(x);
    return (unsigned short)((u + 0x7fffu + ((u >> 16) & 1u)) >> 16);   // RNE
}

// ---- transpose W_enc [H][E][A] f32 -> WencT [H][A][E] bf16 ----
__global__ void k_wenct(const float* __restrict__ Wenc, unsigned short* __restrict__ WencT) {
    __shared__ float tile[32][33];
    int h = blockIdx.z;
    int e0 = blockIdx.x * 32, a0 = blockIdx.y * 32;
    int tx = threadIdx.x, ty = threadIdx.y;   // 32 x 8
    const float* src = Wenc + h * E_ * A_;
    #pragma unroll
    for (int i = 0; i < 4; i++) tile[ty + i*8][tx] = src[(e0 + ty + i*8) * A_ + a0 + tx];
    __syncthreads();
    unsigned short* dst = WencT + h * A_ * E_;
    #pragma unroll
    for (int i = 0; i < 4; i++) dst[(a0 + ty + i*8) * E_ + e0 + tx] = f2bf(tile[tx][ty + i*8]);
}

// ---- W_conv [H][C][A] f32 -> WconvT [H][A][32] bf16 (zero-padded c>=10) ----
__global__ void k_wconvt(const float* __restrict__ Wconv, unsigned short* __restrict__ WconvT) {
    int idx = blockIdx.x * 256 + threadIdx.x;   // H*A*32 = 65536
    int c = idx & 31, a = (idx >> 5) & 511, h = idx >> 14;
    float val = (c < C_) ? Wconv[(h * C_ + c) * A_ + a] : 0.0f;
    WconvT[idx] = f2bf(val);
}

// ---- decA[b][h][a] = sum_d dec[b][d]*W_dec[h][d][a] + b_enc[h][a] ----
__global__ void k_deca(const float* __restrict__ dec, const float* __restrict__ Wdec,
                       const float* __restrict__ benc, float* __restrict__ decA) {
    int bh = blockIdx.x, b = bh >> 2, h = bh & 3;
    int a = threadIdx.x;   // 256 threads, 2 a's each
    float acc0 = 0.f, acc1 = 0.f;
    const float* W = Wdec + h * E_ * A_;
    const float* x = dec + b * 512;
    for (int d = 0; d < 512; d++) {
        float s = x[d];
        acc0 += s * W[d * A_ + a];
        acc1 += s * W[d * A_ + a + 256];
    }
    decA[bh * A_ + a]       = acc0 + benc[h * A_ + a];
    decA[bh * A_ + a + 256] = acc1 + benc[h * A_ + a + 256];
}

// ---- grouped 1D conv (SAME, K=201) -> convA [H][B*T][32] bf16 (pad c>=10 = 0) ----
__global__ void k_conv(const float* __restrict__ aw_step, const float* __restrict__ conv_w,
                       unsigned short* __restrict__ convA) {
    __shared__ float seg[456];
    __shared__ unsigned short outl[8000];
    int b = blockIdx.x, h = blockIdx.y, tc = blockIdx.z;   // tc<6
    int t0 = tc * 250;
    int tid = threadIdx.x;
    for (int idx = tid; idx < 450; idx += 256) {
        int tt = t0 - 100 + idx;
        seg[idx] = (tt >= 0 && tt < T_) ? aw_step[(b * T_ + tt) * H_ + h] : 0.0f;
    }
    for (int idx = tid; idx < 8000; idx += 256) outl[idx] = 0;
    __syncthreads();
    if (tid < 250) {
        float acc[10] = {0,0,0,0,0,0,0,0,0,0};
        const float* cw = conv_w + h * C_ * K_;   // uniform addr -> scalar loads
        for (int k = 0; k < K_; k++) {
            float sv = seg[tid + k];
            #pragma unroll
            for (int c = 0; c < 10; c++) acc[c] += sv * cw[c * K_ + k];
        }
        #pragma unroll
        for (int c = 0; c < 10; c++) outl[tid * 32 + c] = f2bf(acc[c]);
    }
    __syncthreads();
    unsigned short* dst = convA + ((size_t)(h * B_ + b) * T_ + t0) * 32;
    for (int idx = tid; idx < 2000; idx += 256)
        *(ushort4v*)&dst[idx * 4] = *(const ushort4v*)&outl[idx * 4];
}

// ---- fused energy GEMM: energy[b,t,h] = sum_a v[h,a]*tanh(enc@Wenc + conv@Wconv + decA) ----
__launch_bounds__(256, 2)
__global__ void k_energy(const float* __restrict__ enc,
                         const unsigned short* __restrict__ WencT,
                         const unsigned short* __restrict__ convA,
                         const unsigned short* __restrict__ WconvT,
                         const float* __restrict__ decA,
                         const float* __restrict__ v,
                         float* __restrict__ energy) {
    __shared__ unsigned short As[64][552];   // 64 rows x (512 enc + 32 conv + 8 pad)
    __shared__ unsigned short Bs[64][40];    // [n][k] (B^T), pad 40
    int h  = blockIdx.x;     // 4
    int bx = blockIdx.y;     // 375 M-tiles
    int m0 = bx * 64;
    int tid = threadIdx.x;
    int lane = tid & 63, wid = tid >> 6;
    int wr = wid >> 1, wc = wid & 1;
    int lrow = lane & 15, lkb = lane >> 4;

    // stage full-K A-tile: enc (f32->bf16) + conv channels (already bf16)
    #pragma unroll 4
    for (int i = 0; i < 32; i++) {
        int idx = tid + i * 256;           // 8192 float4 loads
        int row = idx >> 7, q = idx & 127;
        const float4 f = *(const float4*)&enc[(size_t)(m0 + row) * 512 + q * 4];
        ushort4v val = { f2bf(f.x), f2bf(f.y), f2bf(f.z), f2bf(f.w) };
        *(ushort4v*)&As[row][q * 4] = val;
    }
    {
        int row = tid >> 2, q = tid & 3;
        *(ushort8v*)&As[row][512 + q * 8] =
            *(const ushort8v*)&convA[(size_t)(h * M_ + m0 + row) * 32 + q * 8];
    }
    __syncthreads();

    for (int nc = 0; nc < 8; nc++) {
        int n0 = nc * 64;
        f32x4 acc[2][2] = {};
        for (int ks = 0; ks < 17; ks++) {
            {   // stage B tile [64 n][32 k]
                int row = tid >> 2, q = tid & 3;
                ushort8v bv;
                if (ks < 16)
                    bv = *(const ushort8v*)&WencT[(size_t)(h * A_ + n0 + row) * E_ + ks * 32 + q * 8];
                else
                    bv = *(const ushort8v*)&WconvT[(size_t)(h * A_ + n0 + row) * 32 + q * 8];
                *(ushort8v*)&Bs[row][q * 8] = bv;
            }
            __syncthreads();
            short8v a0 = *(const short8v*)&As[wr * 32 + lrow][ks * 32 + lkb * 8];
            short8v a1 = *(const short8v*)&As[wr * 32 + 16 + lrow][ks * 32 + lkb * 8];
            short8v b0 = *(const short8v*)&Bs[wc * 32 + lrow][lkb * 8];
            short8v b1 = *(const short8v*)&Bs[wc * 32 + 16 + lrow][lkb * 8];
            acc[0][0] = __builtin_amdgcn_mfma_f32_16x16x32_bf16(a0, b0, acc[0][0], 0, 0, 0);
            acc[0][1] = __builtin_amdgcn_mfma_f32_16x16x32_bf16(a0, b1, acc[0][1], 0, 0, 0);
            acc[1][0] = __builtin_amdgcn_mfma_f32_16x16x32_bf16(a1, b0, acc[1][0], 0, 0, 0);
            acc[1][1] = __builtin_amdgcn_mfma_f32_16x16x32_bf16(a1, b1, acc[1][1], 0, 0, 0);
            __syncthreads();
        }
        // epilogue: bias + tanh + v-dot, reduce over the 64 N-cols of this chunk
        #pragma unroll
        for (int mi = 0; mi < 2; mi++) {
            #pragma unroll
            for (int r = 0; r < 4; r++) {
                int mrow = m0 + wr * 32 + mi * 16 + lkb * 4 + r;
                int bb = mrow / 1500;
                float s = 0.f;
                #pragma unroll
                for (int ni = 0; ni < 2; ni++) {
                    int a_idx = n0 + wc * 32 + ni * 16 + lrow;
                    float x = acc[mi][ni][r] + decA[(bb * H_ + h) * A_ + a_idx];
                    s += v[h * A_ + a_idx] * tanhf(x);
                }
                #pragma unroll
                for (int mk = 1; mk < 16; mk <<= 1) s += __shfl_xor(s, mk);
                if (lrow == 0) atomicAdd(&energy[(size_t)mrow * H_ + h], s);
            }
        }
    }
}

// ---- masked softmax over T (mask zeroes energy, does NOT exclude from softmax) ----
__global__ void k_softmax(const float* __restrict__ energy, const int* __restrict__ xlens,
                          float* __restrict__ aw) {
    __shared__ float red[8];
    int b = blockIdx.x, h = blockIdx.y;
    int tid = threadIdx.x;
    int len = xlens[b];
    float e[6];
    float m = -1e30f;
    #pragma unroll
    for (int i = 0; i < 6; i++) {
        int t = tid + i * 256;
        float val = 0.0f;
        if (t < T_) {
            val = (t < len) ? energy[(size_t)(b * T_ + t) * H_ + h] : 0.0f;
            m = fmaxf(m, val);
        }
        e[i] = val;
    }
    #pragma unroll
    for (int mk = 1; mk < 64; mk <<= 1) m = fmaxf(m, __shfl_xor(m, mk));
    if ((tid & 63) == 0) red[tid >> 6] = m;
    __syncthreads();
    m = fmaxf(fmaxf(red[0], red[1]), fmaxf(red[2], red[3]));
    float ssum = 0.f;
    #pragma unroll
    for (int i = 0; i < 6; i++) {
        int t = tid + i * 256;
        if (t < T_) { e[i] = expf(e[i] - m); ssum += e[i]; }
    }
    #pragma unroll
    for (int mk = 1; mk < 64; mk <<= 1) ssum += __shfl_xor(ssum, mk);
    if ((tid & 63) == 0) red[4 + (tid >> 6)] = ssum;
    __syncthreads();
    float inv = 1.0f / (red[4] + red[5] + red[6] + red[7]);
    #pragma unroll
    for (int i = 0; i < 6; i++) {
        int t = tid + i * 256;
        if (t < T_) aw[(size_t)(b * T_ + t) * H_ + h] = e[i] * inv;
    }
}

// ---- ctx[b][h][e] = sum_t aw[b,t,h] * enc[b,t,e] ----
__global__ void k_ctx(const float* __restrict__ enc, const float* __restrict__ aw,
                      float* __restrict__ ctx) {
    __shared__ float s_aw[500];
    int b = blockIdx.x, eh = blockIdx.y, tc = blockIdx.z;
    int t0 = tc * 125;
    int tid = threadIdx.x;
    for (int idx = tid; idx < 500; idx += 256)
        s_aw[idx] = aw[(size_t)b * T_ * H_ + t0 * H_ + idx];
    __syncthreads();
    int e = eh * 256 + tid;
    float a0 = 0, a1 = 0, a2 = 0, a3 = 0;
    for (int tl = 0; tl < 125; tl++) {
        float ev = enc[(size_t)(b * T_ + t0 + tl) * E_ + e];
        a0 += ev * s_aw[tl * 4 + 0];
        a1 += ev * s_aw[tl * 4 + 1];
        a2 += ev * s_aw[tl * 4 + 2];
        a3 += ev * s_aw[tl * 4 + 3];
    }
    atomicAdd(&ctx[b * 2048 + 0 * 512 + e], a0);
    atomicAdd(&ctx[b * 2048 + 1 * 512 + e], a1);
    atomicAdd(&ctx[b * 2048 + 2 * 512 + e], a2);
    atomicAdd(&ctx[b * 2048 + 3 * 512 + e], a3);
}

// ---- context_vec[b][j] = ctx[b][:] @ W_mha[:,j] + b_mha[j] ----
__global__ void k_proj(const float* __restrict__ ctx, const float* __restrict__ Wmha,
                       const float* __restrict__ bmha, float* __restrict__ out) {
    __shared__ float s_c[256];
    int b = blockIdx.x, ic = blockIdx.y;
    int tid = threadIdx.x;   // 512
    if (tid < 256) s_c[tid] = ctx[b * 2048 + ic * 256 + tid];
    __syncthreads();
    float acc = (ic == 0) ? bmha[tid] : 0.0f;
    const float* W = Wmha + (size_t)ic * 256 * 512;
    for (int i = 0; i < 256; i++) acc += s_c[i] * W[i * 512 + tid];
    atomicAdd(&out[b * 512 + tid], acc);
}

extern "C" void kernel_launch(void* const* d_in, const int* in_sizes, int n_in,
                              void* d_out, int out_size, void* d_ws, size_t ws_size,
                              hipStream_t stream) {
    const float* enc   = (const float*)d_in[0];
    const int*   xlens = (const int*)  d_in[1];
    const float* dec   = (const float*)d_in[2];
    const float* aw_st = (const float*)d_in[3];
    const float* Wenc  = (const float*)d_in[4];
    const float* benc  = (const float*)d_in[5];
    const float* Wdec  = (const float*)d_in[6];
    const float* Wconv = (const float*)d_in[7];
    const float* convw = (const float*)d_in[8];
    const float* v     = (const float*)d_in[9];
    const float* Wmha  = (const float*)d_in[10];
    const float* bmha  = (const float*)d_in[11];
    float* out = (float*)d_out;            // [8192 context_vec][96000 aw]

    char* ws = (char*)d_ws;
    float* energy          = (float*)(ws);                    // 384000 B
    float* ctx             = (float*)(ws + 384000);           // 131072 B
    float* decA            = (float*)(ws + 515072);           // 131072 B
    unsigned short* WencT  = (unsigned short*)(ws + 646144);  // 2097152 B
    unsigned short* WconvT = (unsigned short*)(ws + 2743296); // 131072 B
    unsigned short* convA  = (unsigned short*)(ws + 2874368); // 6144000 B
    float* aw = out + 8192;

    hipMemsetAsync(ws, 0, 515072, stream);                 // energy + ctx accumulators
    hipMemsetAsync(d_out, 0, 8192 * sizeof(float), stream);// context_vec accumulator

    k_wenct  <<<dim3(16, 16, 4), dim3(32, 8), 0, stream>>>(Wenc, WencT);
    k_wconvt <<<256, 256, 0, stream>>>(Wconv, WconvT);
    k_deca   <<<64, 256, 0, stream>>>(dec, Wdec, benc, decA);
    k_conv   <<<dim3(16, 4, 6), 256, 0, stream>>>(aw_st, convw, convA);
    k_energy <<<dim3(4, 375), 256, 0, stream>>>(enc, WencT, convA, WconvT, decA, v, energy);
    k_softmax<<<dim3(16, 4), 256, 0, stream>>>(energy, xlens, aw);
    k_ctx    <<<dim3(16, 2, 12), 256, 0, stream>>>(enc, aw, ctx);
    k_proj   <<<dim3(16, 8), 512, 0, stream>>>(ctx, Wmha, bmha, out);
}

// Round 2
// 252.054 us; speedup vs baseline: 1.4975x; 1.4975x over previous
//
#include <hip/hip_runtime.h>
#include <hip/hip_bf16.h>

#define B_ 16
#define T_ 1500
#define E_ 512
#define A_ 512
#define H_ 4
#define C_ 10
#define K_ 201
#define M_ (B_*T_)   // 24000
#define KW_ 544      // 512 enc + 32 conv-channel K-rows

typedef __attribute__((ext_vector_type(8))) short short8v;    // 8 bf16
typedef __attribute__((ext_vector_type(4))) float f32x4;
typedef __attribute__((ext_vector_type(4))) unsigned short ushort4v;
typedef __attribute__((ext_vector_type(8))) unsigned short ushort8v;

typedef __attribute__((address_space(1))) const char gch;
typedef __attribute__((address_space(3))) char lch;

__device__ inline void gload16(const void* g, void* l) {
    __builtin_amdgcn_global_load_lds((gch*)g, (lch*)l, 16, 0, 0);
}

__device__ inline unsigned short f2bf(float x) {
    unsigned int u = __float_as_uint(x);
    return (unsigned short)((u + 0x7fffu + ((u >> 16) & 1u)) >> 16);   // RNE
}

// ---- enc [24000][512] f32 -> encB bf16 ----
__global__ void k_enc2bf(const float* __restrict__ enc, unsigned short* __restrict__ encB) {
    int i = blockIdx.x * 256 + threadIdx.x;          // 1,536,000 threads, 8 elems each
    const float4* src = (const float4*)enc + (size_t)i * 2;
    float4 f0 = src[0], f1 = src[1];
    ushort8v o = { f2bf(f0.x), f2bf(f0.y), f2bf(f0.z), f2bf(f0.w),
                   f2bf(f1.x), f2bf(f1.y), f2bf(f1.z), f2bf(f1.w) };
    *(ushort8v*)&encB[(size_t)i * 8] = o;
}

// ---- W_enc [H][E][A] f32 -> WencTp [H][A][KW_] bf16 (k<512 section, transposed) ----
__global__ void k_wenct(const float* __restrict__ Wenc, unsigned short* __restrict__ WencTp) {
    __shared__ float tile[32][33];
    int h = blockIdx.z;
    int e0 = blockIdx.x * 32, a0 = blockIdx.y * 32;
    int tx = threadIdx.x, ty = threadIdx.y;   // 32 x 8
    const float* src = Wenc + h * E_ * A_;
    #pragma unroll
    for (int i = 0; i < 4; i++) tile[ty + i*8][tx] = src[(e0 + ty + i*8) * A_ + a0 + tx];
    __syncthreads();
    unsigned short* dst = WencTp + (size_t)h * A_ * KW_;
    #pragma unroll
    for (int i = 0; i < 4; i++) dst[(size_t)(a0 + ty + i*8) * KW_ + e0 + tx] = f2bf(tile[tx][ty + i*8]);
}

// ---- W_conv [H][C][A] f32 -> WencTp k-rows [512,544) (zero-pad c>=10) ----
__global__ void k_wconvpack(const float* __restrict__ Wconv, unsigned short* __restrict__ WencTp) {
    int idx = blockIdx.x * 256 + threadIdx.x;   // 4*512*32 = 65536
    int c = idx & 31, n = (idx >> 5) & 511, h = idx >> 14;
    float val = (c < C_) ? Wconv[(h * C_ + c) * A_ + n] : 0.0f;
    WencTp[((size_t)(h * A_ + n)) * KW_ + 512 + c] = f2bf(val);
}

// ---- decA[b][h][a] = sum_d dec[b][d]*W_dec[h][d][a] + b_enc[h][a] ----
__global__ void k_deca(const float* __restrict__ dec, const float* __restrict__ Wdec,
                       const float* __restrict__ benc, float* __restrict__ decA) {
    int bh = blockIdx.x, b = bh >> 2, h = bh & 3;
    int a = threadIdx.x;
    float acc0 = 0.f, acc1 = 0.f;
    const float* W = Wdec + h * E_ * A_;
    const float* x = dec + b * 512;
    for (int d = 0; d < 512; d++) {
        float s = x[d];
        acc0 += s * W[d * A_ + a];
        acc1 += s * W[d * A_ + a + 256];
    }
    decA[bh * A_ + a]       = acc0 + benc[h * A_ + a];
    decA[bh * A_ + a + 256] = acc1 + benc[h * A_ + a + 256];
}

// ---- grouped 1D conv (SAME, K=201) -> convA [H][M_][32] bf16 (pad c>=10 = 0) ----
__global__ void k_conv(const float* __restrict__ aw_step, const float* __restrict__ conv_w,
                       unsigned short* __restrict__ convA) {
    __shared__ float seg[456];
    __shared__ unsigned short outl[8000];
    int b = blockIdx.x, h = blockIdx.y, tc = blockIdx.z;   // tc<6
    int t0 = tc * 250;
    int tid = threadIdx.x;
    for (int idx = tid; idx < 450; idx += 256) {
        int tt = t0 - 100 + idx;
        seg[idx] = (tt >= 0 && tt < T_) ? aw_step[(b * T_ + tt) * H_ + h] : 0.0f;
    }
    for (int idx = tid; idx < 8000; idx += 256) outl[idx] = 0;
    __syncthreads();
    if (tid < 250) {
        float acc[10] = {0,0,0,0,0,0,0,0,0,0};
        const float* cw = conv_w + h * C_ * K_;
        for (int k = 0; k < K_; k++) {
            float sv = seg[tid + k];
            #pragma unroll
            for (int c = 0; c < 10; c++) acc[c] += sv * cw[c * K_ + k];
        }
        #pragma unroll
        for (int c = 0; c < 10; c++) outl[tid * 32 + c] = f2bf(acc[c]);
    }
    __syncthreads();
    unsigned short* dst = convA + ((size_t)h * M_ + (size_t)b * T_ + t0) * 32;
    for (int idx = tid; idx < 2000; idx += 256)
        *(ushort4v*)&dst[idx * 4] = *(const ushort4v*)&outl[idx * 4];
}

// ---- fused energy GEMM (m97-style 128x128, BK=64, global_load_lds) ----
__launch_bounds__(256)
__global__ void k_energy(const unsigned short* __restrict__ encB,
                         const unsigned short* __restrict__ WencTp,
                         const unsigned short* __restrict__ convA,
                         const float* __restrict__ decA,
                         const float* __restrict__ v,
                         float* __restrict__ energy) {
    __shared__ unsigned short As[128 * 64];
    __shared__ unsigned short Bs[128 * 64];
    int m0 = blockIdx.x * 128;                // 188 M-tiles (last clamps rows)
    int h  = blockIdx.y >> 2;
    int n0 = (blockIdx.y & 3) * 128;
    int tid = threadIdx.x;
    int lane = tid & 63, w = tid >> 6;
    int wr = w >> 1, wc = w & 1;
    int lc = lane & 15, lr16 = lane >> 4;

    f32x4 acc[4][4] = {};

    // 8 enc K-steps of BK=64
    for (int s = 0; s < 8; ++s) {
        #pragma unroll
        for (int i = 0; i < 4; ++i) {
            int c = i * 4 + w;
            int tb = c * 1024 + lane * 16;
            int row = tb >> 7, colb = tb & 127;
            int grow = min(m0 + row, M_ - 1);
            gload16((const char*)encB + ((size_t)grow * 512 + s * 64) * 2 + colb,
                    (char*)As + c * 1024);
            gload16((const char*)WencTp + ((size_t)(h * 512 + n0 + row) * KW_ + s * 64) * 2 + colb,
                    (char*)Bs + c * 1024);
        }
        __syncthreads();
        #pragma unroll
        for (int ksub = 0; ksub < 2; ++ksub) {
            short8v a[4], b[4];
            #pragma unroll
            for (int mi = 0; mi < 4; mi++)
                a[mi] = *(const short8v*)&As[(wr * 64 + mi * 16 + lc) * 64 + ksub * 32 + lr16 * 8];
            #pragma unroll
            for (int ni = 0; ni < 4; ni++)
                b[ni] = *(const short8v*)&Bs[(wc * 64 + ni * 16 + lc) * 64 + ksub * 32 + lr16 * 8];
            #pragma unroll
            for (int mi = 0; mi < 4; mi++)
                #pragma unroll
                for (int ni = 0; ni < 4; ni++)
                    acc[mi][ni] = __builtin_amdgcn_mfma_f32_16x16x32_bf16(a[mi], b[ni], acc[mi][ni], 0, 0, 0);
        }
        __syncthreads();
    }

    // conv K-step: BK=32, A from convA [h][m][32], B from WencTp k-rows [512,544)
    {
        #pragma unroll
        for (int i = 0; i < 2; ++i) {
            int c = i * 4 + w;
            int tb = c * 1024 + lane * 16;
            int row = tb >> 6, colb = tb & 63;
            int grow = min(m0 + row, M_ - 1);
            gload16((const char*)convA + ((size_t)h * M_ + grow) * 64 + colb,
                    (char*)As + c * 1024);
            gload16((const char*)WencTp + ((size_t)(h * 512 + n0 + row) * KW_ + 512) * 2 + colb,
                    (char*)Bs + c * 1024);
        }
        __syncthreads();
        short8v a[4], b[4];
        #pragma unroll
        for (int mi = 0; mi < 4; mi++)
            a[mi] = *(const short8v*)&As[(wr * 64 + mi * 16 + lc) * 32 + lr16 * 8];
        #pragma unroll
        for (int ni = 0; ni < 4; ni++)
            b[ni] = *(const short8v*)&Bs[(wc * 64 + ni * 16 + lc) * 32 + lr16 * 8];
        #pragma unroll
        for (int mi = 0; mi < 4; mi++)
            #pragma unroll
            for (int ni = 0; ni < 4; ni++)
                acc[mi][ni] = __builtin_amdgcn_mfma_f32_16x16x32_bf16(a[mi], b[ni], acc[mi][ni], 0, 0, 0);
        __syncthreads();
    }

    // epilogue: bias + tanh + v-dot over this block's 128 N-cols, then atomic partial
    #pragma unroll
    for (int mi = 0; mi < 4; mi++) {
        #pragma unroll
        for (int r = 0; r < 4; r++) {
            int mrow = m0 + wr * 64 + mi * 16 + lr16 * 4 + r;
            if (mrow < M_) {
                int bb = mrow / 1500;
                const float* dA = decA + (bb * 4 + h) * 512;
                float s = 0.f;
                #pragma unroll
                for (int ni = 0; ni < 4; ni++) {
                    int n = n0 + wc * 64 + ni * 16 + lc;
                    float x = acc[mi][ni][r] + dA[n];
                    x = fminf(fmaxf(x, -15.f), 15.f);
                    float e2 = __expf(2.0f * x);
                    s += v[h * 512 + n] * ((e2 - 1.0f) * __builtin_amdgcn_rcpf(e2 + 1.0f));
                }
                #pragma unroll
                for (int mk = 1; mk < 16; mk <<= 1) s += __shfl_xor(s, mk);
                if (lc == 0) atomicAdd(&energy[(size_t)mrow * 4 + h], s);
            }
        }
    }
}

// ---- masked softmax over T ----
__global__ void k_softmax(const float* __restrict__ energy, const int* __restrict__ xlens,
                          float* __restrict__ aw) {
    __shared__ float red[8];
    int b = blockIdx.x, h = blockIdx.y;
    int tid = threadIdx.x;
    int len = xlens[b];
    float e[6];
    float m = -1e30f;
    #pragma unroll
    for (int i = 0; i < 6; i++) {
        int t = tid + i * 256;
        float val = 0.0f;
        if (t < T_) {
            val = (t < len) ? energy[(size_t)(b * T_ + t) * H_ + h] : 0.0f;
            m = fmaxf(m, val);
        }
        e[i] = val;
    }
    #pragma unroll
    for (int mk = 1; mk < 64; mk <<= 1) m = fmaxf(m, __shfl_xor(m, mk));
    if ((tid & 63) == 0) red[tid >> 6] = m;
    __syncthreads();
    m = fmaxf(fmaxf(red[0], red[1]), fmaxf(red[2], red[3]));
    float ssum = 0.f;
    #pragma unroll
    for (int i = 0; i < 6; i++) {
        int t = tid + i * 256;
        if (t < T_) { e[i] = expf(e[i] - m); ssum += e[i]; }
    }
    #pragma unroll
    for (int mk = 1; mk < 64; mk <<= 1) ssum += __shfl_xor(ssum, mk);
    if ((tid & 63) == 0) red[4 + (tid >> 6)] = ssum;
    __syncthreads();
    float inv = 1.0f / (red[4] + red[5] + red[6] + red[7]);
    #pragma unroll
    for (int i = 0; i < 6; i++) {
        int t = tid + i * 256;
        if (t < T_) aw[(size_t)(b * T_ + t) * H_ + h] = e[i] * inv;
    }
}

// ---- ctx[b][h][e] = sum_t aw[b,t,h] * enc[b,t,e] ----
__global__ void k_ctx(const float* __restrict__ enc, const float* __restrict__ aw,
                      float* __restrict__ ctx) {
    __shared__ float s_aw[500];
    int b = blockIdx.x, eh = blockIdx.y, tc = blockIdx.z;
    int t0 = tc * 125;
    int tid = threadIdx.x;
    for (int idx = tid; idx < 500; idx += 256)
        s_aw[idx] = aw[(size_t)b * T_ * H_ + t0 * H_ + idx];
    __syncthreads();
    int e = eh * 256 + tid;
    float a0 = 0, a1 = 0, a2 = 0, a3 = 0;
    for (int tl = 0; tl < 125; tl++) {
        float ev = enc[(size_t)(b * T_ + t0 + tl) * E_ + e];
        a0 += ev * s_aw[tl * 4 + 0];
        a1 += ev * s_aw[tl * 4 + 1];
        a2 += ev * s_aw[tl * 4 + 2];
        a3 += ev * s_aw[tl * 4 + 3];
    }
    atomicAdd(&ctx[b * 2048 + 0 * 512 + e], a0);
    atomicAdd(&ctx[b * 2048 + 1 * 512 + e], a1);
    atomicAdd(&ctx[b * 2048 + 2 * 512 + e], a2);
    atomicAdd(&ctx[b * 2048 + 3 * 512 + e], a3);
}

// ---- context_vec[b][j] = ctx[b][:] @ W_mha[:,j] + b_mha[j] ----
__global__ void k_proj(const float* __restrict__ ctx, const float* __restrict__ Wmha,
                       const float* __restrict__ bmha, float* __restrict__ out) {
    __shared__ float s_c[256];
    int b = blockIdx.x, ic = blockIdx.y;
    int tid = threadIdx.x;   // 512
    if (tid < 256) s_c[tid] = ctx[b * 2048 + ic * 256 + tid];
    __syncthreads();
    float acc = (ic == 0) ? bmha[tid] : 0.0f;
    const float* W = Wmha + (size_t)ic * 256 * 512;
    for (int i = 0; i < 256; i++) acc += s_c[i] * W[i * 512 + tid];
    atomicAdd(&out[b * 512 + tid], acc);
}

extern "C" void kernel_launch(void* const* d_in, const int* in_sizes, int n_in,
                              void* d_out, int out_size, void* d_ws, size_t ws_size,
                              hipStream_t stream) {
    const float* enc   = (const float*)d_in[0];
    const int*   xlens = (const int*)  d_in[1];
    const float* dec   = (const float*)d_in[2];
    const float* aw_st = (const float*)d_in[3];
    const float* Wenc  = (const float*)d_in[4];
    const float* benc  = (const float*)d_in[5];
    const float* Wdec  = (const float*)d_in[6];
    const float* Wconv = (const float*)d_in[7];
    const float* convw = (const float*)d_in[8];
    const float* v     = (const float*)d_in[9];
    const float* Wmha  = (const float*)d_in[10];
    const float* bmha  = (const float*)d_in[11];
    float* out = (float*)d_out;            // [8192 context_vec][96000 aw]

    char* ws = (char*)d_ws;
    float* energy          = (float*)(ws);                    // 384000 B
    float* ctx             = (float*)(ws + 384000);           // 131072 B
    float* decA            = (float*)(ws + 515072);           // 131072 B
    unsigned short* WencTp = (unsigned short*)(ws + 646144);  // 4*512*544*2 = 2228224 B
    unsigned short* convA  = (unsigned short*)(ws + 2874368); // 4*24000*32*2 = 6144000 B
    unsigned short* encB   = (unsigned short*)(ws + 9018368); // 24000*512*2 = 24576000 B
    float* aw = out + 8192;

    hipMemsetAsync(ws, 0, 515072, stream);                 // energy + ctx accumulators
    hipMemsetAsync(d_out, 0, 8192 * sizeof(float), stream);// context_vec accumulator

    k_enc2bf    <<<6000, 256, 0, stream>>>(enc, encB);
    k_wenct     <<<dim3(16, 16, 4), dim3(32, 8), 0, stream>>>(Wenc, WencTp);
    k_wconvpack <<<256, 256, 0, stream>>>(Wconv, WencTp);
    k_deca      <<<64, 256, 0, stream>>>(dec, Wdec, benc, decA);
    k_conv      <<<dim3(16, 4, 6), 256, 0, stream>>>(aw_st, convw, convA);
    k_energy    <<<dim3(188, 16), 256, 0, stream>>>(encB, WencTp, convA, decA, v, energy);
    k_softmax   <<<dim3(16, 4), 256, 0, stream>>>(energy, xlens, aw);
    k_ctx       <<<dim3(16, 2, 12), 256, 0, stream>>>(enc, aw, ctx);
    k_proj      <<<dim3(16, 8), 512, 0, stream>>>(ctx, Wmha, bmha, out);
}

// Round 3
// 214.225 us; speedup vs baseline: 1.7619x; 1.1766x over previous
//
#include <hip/hip_runtime.h>
#include <hip/hip_bf16.h>

#define B_ 16
#define T_ 1500
#define E_ 512
#define A_ 512
#define H_ 4
#define C_ 10
#define K_ 201
#define M_ (B_*T_)   // 24000
#define KW_ 544      // 512 enc + 32 conv-channel K-rows

typedef __attribute__((ext_vector_type(8))) short short8v;    // 8 bf16
typedef __attribute__((ext_vector_type(4))) float f32x4;
typedef __attribute__((ext_vector_type(4))) unsigned short ushort4v;
typedef __attribute__((ext_vector_type(8))) unsigned short ushort8v;

typedef __attribute__((address_space(1))) const char gch;
typedef __attribute__((address_space(3))) char lch;

__device__ inline void gload16(const void* g, void* l) {
    __builtin_amdgcn_global_load_lds((gch*)g, (lch*)l, 16, 0, 0);
}

__device__ inline unsigned short f2bf(float x) {
    unsigned int u = __float_as_uint(x);
    return (unsigned short)((u + 0x7fffu + ((u >> 16) & 1u)) >> 16);   // RNE
}

// ---- enc [24000][512] f32 -> encB bf16 ----
__global__ void k_enc2bf(const float* __restrict__ enc, unsigned short* __restrict__ encB) {
    int i = blockIdx.x * 256 + threadIdx.x;
    const float4* src = (const float4*)enc + (size_t)i * 2;
    float4 f0 = src[0], f1 = src[1];
    ushort8v o = { f2bf(f0.x), f2bf(f0.y), f2bf(f0.z), f2bf(f0.w),
                   f2bf(f1.x), f2bf(f1.y), f2bf(f1.z), f2bf(f1.w) };
    *(ushort8v*)&encB[(size_t)i * 8] = o;
}

// ---- W_enc [H][E][A] f32 -> WencTp [H][A][KW_] bf16 (k<512 section, transposed) ----
__global__ void k_wenct(const float* __restrict__ Wenc, unsigned short* __restrict__ WencTp) {
    __shared__ float tile[32][33];
    int h = blockIdx.z;
    int e0 = blockIdx.x * 32, a0 = blockIdx.y * 32;
    int tx = threadIdx.x, ty = threadIdx.y;   // 32 x 8
    const float* src = Wenc + h * E_ * A_;
    #pragma unroll
    for (int i = 0; i < 4; i++) tile[ty + i*8][tx] = src[(e0 + ty + i*8) * A_ + a0 + tx];
    __syncthreads();
    unsigned short* dst = WencTp + (size_t)h * A_ * KW_;
    #pragma unroll
    for (int i = 0; i < 4; i++) dst[(size_t)(a0 + ty + i*8) * KW_ + e0 + tx] = f2bf(tile[tx][ty + i*8]);
}

// ---- W_conv [H][C][A] f32 -> WencTp k-rows [512,544) (zero-pad c>=10) ----
__global__ void k_wconvpack(const float* __restrict__ Wconv, unsigned short* __restrict__ WencTp) {
    int idx = blockIdx.x * 256 + threadIdx.x;   // 4*512*32 = 65536
    int c = idx & 31, n = (idx >> 5) & 511, h = idx >> 14;
    float val = (c < C_) ? Wconv[(h * C_ + c) * A_ + n] : 0.0f;
    WencTp[((size_t)(h * A_ + n)) * KW_ + 512 + c] = f2bf(val);
}

// ---- decA[b][h][a] = sum_d dec[b][d]*W_dec[h][d][a] + b_enc[h][a] ----
__global__ void k_deca(const float* __restrict__ dec, const float* __restrict__ Wdec,
                       const float* __restrict__ benc, float* __restrict__ decA) {
    int bh = blockIdx.x, b = bh >> 2, h = bh & 3;
    int a = threadIdx.x;
    float acc0 = 0.f, acc1 = 0.f;
    const float* W = Wdec + h * E_ * A_;
    const float* x = dec + b * 512;
    for (int d = 0; d < 512; d++) {
        float s = x[d];
        acc0 += s * W[d * A_ + a];
        acc1 += s * W[d * A_ + a + 256];
    }
    decA[bh * A_ + a]       = acc0 + benc[h * A_ + a];
    decA[bh * A_ + a + 256] = acc1 + benc[h * A_ + a + 256];
}

// ---- grouped 1D conv (SAME, K=201) -> convA [H][M_][32] bf16 (pad c>=10 = 0) ----
__global__ void k_conv(const float* __restrict__ aw_step, const float* __restrict__ conv_w,
                       unsigned short* __restrict__ convA) {
    __shared__ float seg[456];
    __shared__ unsigned short outl[8000];
    int b = blockIdx.x, h = blockIdx.y, tc = blockIdx.z;   // tc<6
    int t0 = tc * 250;
    int tid = threadIdx.x;
    for (int idx = tid; idx < 450; idx += 256) {
        int tt = t0 - 100 + idx;
        seg[idx] = (tt >= 0 && tt < T_) ? aw_step[(b * T_ + tt) * H_ + h] : 0.0f;
    }
    for (int idx = tid; idx < 8000; idx += 256) outl[idx] = 0;
    __syncthreads();
    if (tid < 250) {
        float acc[10] = {0,0,0,0,0,0,0,0,0,0};
        const float* cw = conv_w + h * C_ * K_;
        for (int k = 0; k < K_; k++) {
            float sv = seg[tid + k];
            #pragma unroll
            for (int c = 0; c < 10; c++) acc[c] += sv * cw[c * K_ + k];
        }
        #pragma unroll
        for (int c = 0; c < 10; c++) outl[tid * 32 + c] = f2bf(acc[c]);
    }
    __syncthreads();
    unsigned short* dst = convA + ((size_t)h * M_ + (size_t)b * T_ + t0) * 32;
    for (int idx = tid; idx < 2000; idx += 256)
        *(ushort4v*)&dst[idx * 4] = *(const ushort4v*)&outl[idx * 4];
}

// ---- fused energy GEMM (128x128, BK=64, global_load_lds, XOR-swizzled LDS) ----
// Swizzle (both-sides, rule #21): LDS dest linear; global source col16 ^= row&7;
// ds_read slot ^= row&7. Involution: read(slot j^r) -> stored global (j^r)^r = j.
__launch_bounds__(256)
__global__ void k_energy(const unsigned short* __restrict__ encB,
                         const unsigned short* __restrict__ WencTp,
                         const unsigned short* __restrict__ convA,
                         const float* __restrict__ decA,
                         const float* __restrict__ v,
                         float* __restrict__ energy) {
    __shared__ unsigned short As[128 * 64];
    __shared__ unsigned short Bs[128 * 64];
    int m0 = blockIdx.x * 128;                // 188 M-tiles (last clamps rows)
    int h  = blockIdx.y >> 2;
    int n0 = (blockIdx.y & 3) * 128;
    int tid = threadIdx.x;
    int lane = tid & 63, w = tid >> 6;
    int wr = w >> 1, wc = w & 1;
    int lc = lane & 15, lr16 = lane >> 4;

    // staging lane decomposition (BK=64: 8 x 16B slots per row, chunk = 8 rows)
    int srow8 = lane >> 3;                    // row within chunk (0..7)
    int sslot8 = (lane & 7) ^ (srow8 & 7);    // swizzled 16B slot (0..7)
    // conv step (BK=32: 4 slots per row, chunk = 16 rows)
    int srow16 = lane >> 2;
    int sslot4 = (lane & 3) ^ (srow16 & 3);

    f32x4 acc[4][4] = {};

    // 8 enc K-steps of BK=64
    for (int s = 0; s < 8; ++s) {
        #pragma unroll
        for (int i = 0; i < 4; ++i) {
            int c = i * 4 + w;                // chunk 0..15, rows c*8..c*8+7
            int row = c * 8 + srow8;
            int grow = min(m0 + row, M_ - 1);
            gload16((const char*)encB + ((size_t)grow * 512 + s * 64 + sslot8 * 8) * 2,
                    (char*)As + c * 1024);
            gload16((const char*)WencTp + ((size_t)(h * 512 + n0 + row) * KW_ + s * 64 + sslot8 * 8) * 2,
                    (char*)Bs + c * 1024);
        }
        __syncthreads();
        #pragma unroll
        for (int ksub = 0; ksub < 2; ++ksub) {
            short8v a[4], b[4];
            #pragma unroll
            for (int mi = 0; mi < 4; mi++) {
                int row = wr * 64 + mi * 16 + lc;
                a[mi] = *(const short8v*)&As[row * 64 + ((ksub * 4 + lr16) ^ (lc & 7)) * 8];
            }
            #pragma unroll
            for (int ni = 0; ni < 4; ni++) {
                int row = wc * 64 + ni * 16 + lc;
                b[ni] = *(const short8v*)&Bs[row * 64 + ((ksub * 4 + lr16) ^ (lc & 7)) * 8];
            }
            #pragma unroll
            for (int mi = 0; mi < 4; mi++)
                #pragma unroll
                for (int ni = 0; ni < 4; ni++)
                    acc[mi][ni] = __builtin_amdgcn_mfma_f32_16x16x32_bf16(a[mi], b[ni], acc[mi][ni], 0, 0, 0);
        }
        __syncthreads();
    }

    // conv K-step: BK=32, A from convA [h][m][32], B from WencTp k-rows [512,544)
    {
        #pragma unroll
        for (int i = 0; i < 2; ++i) {
            int c = i * 4 + w;                // chunk 0..7, rows c*16..c*16+15
            int row = c * 16 + srow16;
            int grow = min(m0 + row, M_ - 1);
            gload16((const char*)convA + (((size_t)h * M_ + grow) * 32 + sslot4 * 8) * 2,
                    (char*)As + c * 1024);
            gload16((const char*)WencTp + (((size_t)(h * 512 + n0 + row)) * KW_ + 512 + sslot4 * 8) * 2,
                    (char*)Bs + c * 1024);
        }
        __syncthreads();
        short8v a[4], b[4];
        #pragma unroll
        for (int mi = 0; mi < 4; mi++) {
            int row = wr * 64 + mi * 16 + lc;
            a[mi] = *(const short8v*)&As[row * 32 + (lr16 ^ (lc & 3)) * 8];
        }
        #pragma unroll
        for (int ni = 0; ni < 4; ni++) {
            int row = wc * 64 + ni * 16 + lc;
            b[ni] = *(const short8v*)&Bs[row * 32 + (lr16 ^ (lc & 3)) * 8];
        }
        #pragma unroll
        for (int mi = 0; mi < 4; mi++)
            #pragma unroll
            for (int ni = 0; ni < 4; ni++)
                acc[mi][ni] = __builtin_amdgcn_mfma_f32_16x16x32_bf16(a[mi], b[ni], acc[mi][ni], 0, 0, 0);
        __syncthreads();
    }

    // epilogue: bias + tanh + v-dot over this block's 128 N-cols, then atomic partial
    #pragma unroll
    for (int mi = 0; mi < 4; mi++) {
        #pragma unroll
        for (int r = 0; r < 4; r++) {
            int mrow = m0 + wr * 64 + mi * 16 + lr16 * 4 + r;
            if (mrow < M_) {
                int bb = mrow / 1500;
                const float* dA = decA + (bb * 4 + h) * 512;
                float s = 0.f;
                #pragma unroll
                for (int ni = 0; ni < 4; ni++) {
                    int n = n0 + wc * 64 + ni * 16 + lc;
                    float x = acc[mi][ni][r] + dA[n];
                    x = fminf(fmaxf(x, -15.f), 15.f);
                    float e2 = __expf(2.0f * x);
                    s += v[h * 512 + n] * ((e2 - 1.0f) * __builtin_amdgcn_rcpf(e2 + 1.0f));
                }
                #pragma unroll
                for (int mk = 1; mk < 16; mk <<= 1) s += __shfl_xor(s, mk);
                if (lc == 0) atomicAdd(&energy[(size_t)mrow * 4 + h], s);
            }
        }
    }
}

// ---- masked softmax over T ----
__global__ void k_softmax(const float* __restrict__ energy, const int* __restrict__ xlens,
                          float* __restrict__ aw) {
    __shared__ float red[8];
    int b = blockIdx.x, h = blockIdx.y;
    int tid = threadIdx.x;
    int len = xlens[b];
    float e[6];
    float m = -1e30f;
    #pragma unroll
    for (int i = 0; i < 6; i++) {
        int t = tid + i * 256;
        float val = 0.0f;
        if (t < T_) {
            val = (t < len) ? energy[(size_t)(b * T_ + t) * H_ + h] : 0.0f;
            m = fmaxf(m, val);
        }
        e[i] = val;
    }
    #pragma unroll
    for (int mk = 1; mk < 64; mk <<= 1) m = fmaxf(m, __shfl_xor(m, mk));
    if ((tid & 63) == 0) red[tid >> 6] = m;
    __syncthreads();
    m = fmaxf(fmaxf(red[0], red[1]), fmaxf(red[2], red[3]));
    float ssum = 0.f;
    #pragma unroll
    for (int i = 0; i < 6; i++) {
        int t = tid + i * 256;
        if (t < T_) { e[i] = expf(e[i] - m); ssum += e[i]; }
    }
    #pragma unroll
    for (int mk = 1; mk < 64; mk <<= 1) ssum += __shfl_xor(ssum, mk);
    if ((tid & 63) == 0) red[4 + (tid >> 6)] = ssum;
    __syncthreads();
    float inv = 1.0f / (red[4] + red[5] + red[6] + red[7]);
    #pragma unroll
    for (int i = 0; i < 6; i++) {
        int t = tid + i * 256;
        if (t < T_) aw[(size_t)(b * T_ + t) * H_ + h] = e[i] * inv;
    }
}

// ---- ctx[b][h][e] = sum_t aw[b,t,h] * enc[b,t,e] ----
__global__ void k_ctx(const float* __restrict__ enc, const float* __restrict__ aw,
                      float* __restrict__ ctx) {
    __shared__ float s_aw[500];
    int b = blockIdx.x, eh = blockIdx.y, tc = blockIdx.z;
    int t0 = tc * 125;
    int tid = threadIdx.x;
    for (int idx = tid; idx < 500; idx += 256)
        s_aw[idx] = aw[(size_t)b * T_ * H_ + t0 * H_ + idx];
    __syncthreads();
    int e = eh * 256 + tid;
    float a0 = 0, a1 = 0, a2 = 0, a3 = 0;
    for (int tl = 0; tl < 125; tl++) {
        float ev = enc[(size_t)(b * T_ + t0 + tl) * E_ + e];
        a0 += ev * s_aw[tl * 4 + 0];
        a1 += ev * s_aw[tl * 4 + 1];
        a2 += ev * s_aw[tl * 4 + 2];
        a3 += ev * s_aw[tl * 4 + 3];
    }
    atomicAdd(&ctx[b * 2048 + 0 * 512 + e], a0);
    atomicAdd(&ctx[b * 2048 + 1 * 512 + e], a1);
    atomicAdd(&ctx[b * 2048 + 2 * 512 + e], a2);
    atomicAdd(&ctx[b * 2048 + 3 * 512 + e], a3);
}

// ---- context_vec[b][j] = ctx[b][:] @ W_mha[:,j] + b_mha[j] ----
__global__ void k_proj(const float* __restrict__ ctx, const float* __restrict__ Wmha,
                       const float* __restrict__ bmha, float* __restrict__ out) {
    __shared__ float s_c[256];
    int b = blockIdx.x, ic = blockIdx.y;
    int tid = threadIdx.x;   // 512
    if (tid < 256) s_c[tid] = ctx[b * 2048 + ic * 256 + tid];
    __syncthreads();
    float acc = (ic == 0) ? bmha[tid] : 0.0f;
    const float* W = Wmha + (size_t)ic * 256 * 512;
    for (int i = 0; i < 256; i++) acc += s_c[i] * W[i * 512 + tid];
    atomicAdd(&out[b * 512 + tid], acc);
}

extern "C" void kernel_launch(void* const* d_in, const int* in_sizes, int n_in,
                              void* d_out, int out_size, void* d_ws, size_t ws_size,
                              hipStream_t stream) {
    const float* enc   = (const float*)d_in[0];
    const int*   xlens = (const int*)  d_in[1];
    const float* dec   = (const float*)d_in[2];
    const float* aw_st = (const float*)d_in[3];
    const float* Wenc  = (const float*)d_in[4];
    const float* benc  = (const float*)d_in[5];
    const float* Wdec  = (const float*)d_in[6];
    const float* Wconv = (const float*)d_in[7];
    const float* convw = (const float*)d_in[8];
    const float* v     = (const float*)d_in[9];
    const float* Wmha  = (const float*)d_in[10];
    const float* bmha  = (const float*)d_in[11];
    float* out = (float*)d_out;            // [8192 context_vec][96000 aw]

    char* ws = (char*)d_ws;
    float* energy          = (float*)(ws);                    // 384000 B
    float* ctx             = (float*)(ws + 384000);           // 131072 B
    float* decA            = (float*)(ws + 515072);           // 131072 B
    unsigned short* WencTp = (unsigned short*)(ws + 646144);  // 4*512*544*2 = 2228224 B
    unsigned short* convA  = (unsigned short*)(ws + 2874368); // 4*24000*32*2 = 6144000 B
    unsigned short* encB   = (unsigned short*)(ws + 9018368); // 24000*512*2 = 24576000 B
    float* aw = out + 8192;

    hipMemsetAsync(ws, 0, 515072, stream);                 // energy + ctx accumulators
    hipMemsetAsync(d_out, 0, 8192 * sizeof(float), stream);// context_vec accumulator

    k_enc2bf    <<<6000, 256, 0, stream>>>(enc, encB);
    k_wenct     <<<dim3(16, 16, 4), dim3(32, 8), 0, stream>>>(Wenc, WencTp);
    k_wconvpack <<<256, 256, 0, stream>>>(Wconv, WencTp);
    k_deca      <<<64, 256, 0, stream>>>(dec, Wdec, benc, decA);
    k_conv      <<<dim3(16, 4, 6), 256, 0, stream>>>(aw_st, convw, convA);
    k_energy    <<<dim3(188, 16), 256, 0, stream>>>(encB, WencTp, convA, decA, v, energy);
    k_softmax   <<<dim3(16, 4), 256, 0, stream>>>(energy, xlens, aw);
    k_ctx       <<<dim3(16, 2, 12), 256, 0, stream>>>(enc, aw, ctx);
    k_proj      <<<dim3(16, 8), 512, 0, stream>>>(ctx, Wmha, bmha, out);
}